// Round 1
// baseline (149.998 us; speedup 1.0000x reference)
//
#include <hip/hip_runtime.h>

#define TT 64
#define NSEQ 128
#define NPAIR (NSEQ * NSEQ)
#define DIM 13
#define INFV 1e10f
#define YSTR 20   // floats per LDS y-row: 80 B, 16B-aligned, quad-rotating stride

// soft-min constants: gamma = 0.1
#define C_EXP 14.4269504088896f   // (1/gamma) * log2(e)
#define C_LOG 0.0693147180560f    // gamma * ln(2)

__global__ __launch_bounds__(256) void sdtw_pairs(const float* __restrict__ xxx,
                                                  const float* __restrict__ yyy,
                                                  float* __restrict__ simR) {
    __shared__ float ylds[4][TT * YSTR];
    const int wave = threadIdx.x >> 6;
    const int lane = threadIdx.x & 63;
    const int p = blockIdx.x * 4 + wave;      // pair index 0..16383
    const int a = p >> 7;
    const int b = p & (NSEQ - 1);
    const float* fa = (a < 64) ? (xxx + (size_t)a * TT * DIM) : (yyy + (size_t)(a - 64) * TT * DIM);
    const float* fb = (b < 64) ? (xxx + (size_t)b * TT * DIM) : (yyy + (size_t)(b - 64) * TT * DIM);

    // lane i holds x_i (scaled by -2) and sqx_i; lane j loads y_j and stages it to LDS
    float xm[DIM];
    float sqx = 0.f, sqy = 0.f;
    float yv[DIM];
#pragma unroll
    for (int c = 0; c < DIM; c++) {
        float xc = fa[lane * DIM + c];
        float yc = fb[lane * DIM + c];
        sqx += xc * xc;
        sqy += yc * yc;
        xm[c] = -2.f * xc;
        yv[c] = yc;
    }
    float* row = &ylds[wave][lane * YSTR];
#pragma unroll
    for (int c = 0; c < DIM; c++) row[c] = yv[c];
    row[13] = sqy;
    __syncthreads();

    const float* yw = ylds[wave];
    float Rm1 = INFV, Rm2 = INFV;
    float corner = 0.f;   // r_diag injected at lane 0, k==0 only; becomes INF after
    const bool lane0 = (lane == 0);

#pragma unroll 2
    for (int k = 0; k < 2 * TT - 1; k++) {
        int j = k - lane;
        bool valid = (j >= 0) && (j < TT);
        int jc = min(max(j, 0), TT - 1);
        const float* rp = yw + jc * YSTR;
        float4 v0 = *(const float4*)(rp);
        float4 v1 = *(const float4*)(rp + 4);
        float4 v2 = *(const float4*)(rp + 8);
        float2 v3 = *(const float2*)(rp + 12);   // y12, sqy

        float acc = sqx + v3.y;
        acc = fmaf(xm[0],  v0.x, acc);
        acc = fmaf(xm[1],  v0.y, acc);
        acc = fmaf(xm[2],  v0.z, acc);
        acc = fmaf(xm[3],  v0.w, acc);
        acc = fmaf(xm[4],  v1.x, acc);
        acc = fmaf(xm[5],  v1.y, acc);
        acc = fmaf(xm[6],  v1.z, acc);
        acc = fmaf(xm[7],  v1.w, acc);
        acc = fmaf(xm[8],  v2.x, acc);
        acc = fmaf(xm[9],  v2.y, acc);
        acc = fmaf(xm[10], v2.z, acc);
        acc = fmaf(xm[11], v2.w, acc);
        acc = fmaf(xm[12], v3.x, acc);

        float up = __shfl_up(Rm1, 1);
        float dg = __shfl_up(Rm2, 1);
        up = lane0 ? INFV : up;
        dg = lane0 ? corner : dg;
        float left = Rm1;

        float m = fminf(fminf(up, left), dg);
        float e0 = __builtin_amdgcn_exp2f((m - up)   * C_EXP);
        float e1 = __builtin_amdgcn_exp2f((m - left) * C_EXP);
        float e2 = __builtin_amdgcn_exp2f((m - dg)   * C_EXP);
        float sm = m - C_LOG * __builtin_amdgcn_logf(e0 + e1 + e2);

        float Rn = valid ? (acc + sm) : INFV;
        Rm2 = Rm1;
        Rm1 = Rn;
        corner = INFV;
    }

    if (lane == 63) simR[p] = Rm1;   // R(T-1, T-1)
}

__global__ void contrastive_loss(const float* __restrict__ simR, float* __restrict__ out) {
    __shared__ float red[NSEQ];
    const int r = threadIdx.x;   // 0..127
    const float* rowp = simR + r * NSEQ;

    float mx = -3.4e38f;
    for (int c = 0; c < NSEQ; c++) {
        float v = (c == r) ? 0.f : 2.f * rowp[c];   // sim = R / ENERGY, diag zeroed
        mx = fmaxf(mx, v);
    }
    float s = 0.f;
    for (int c = 0; c < NSEQ; c++) {
        float v = (c == r) ? 0.f : 2.f * rowp[c];
        s += expf(v - mx);
    }
    float lse = mx + logf(s);

    const int i = r & 63;
    float pos = 2.f * simR[i * NSEQ + i + 64];   // sim[i, i+64]
    red[r] = lse - pos;
    __syncthreads();
    if (r == 0) {
        float t = 0.f;
        for (int c = 0; c < NSEQ; c++) t += red[c];
        out[0] = t / (float)NSEQ;
    }
}

extern "C" void kernel_launch(void* const* d_in, const int* in_sizes, int n_in,
                              void* d_out, int out_size, void* d_ws, size_t ws_size,
                              hipStream_t stream) {
    const float* xxx = (const float*)d_in[0];
    const float* yyy = (const float*)d_in[1];
    float* out = (float*)d_out;
    float* simR = (float*)d_ws;   // 16384 floats = 64 KB

    sdtw_pairs<<<NPAIR / 4, 256, 0, stream>>>(xxx, yyy, simR);
    contrastive_loss<<<1, NSEQ, 0, stream>>>(simR, out);
}

// Round 2
// 63.348 us; speedup vs baseline: 2.3678x; 2.3678x over previous
//
#include <hip/hip_runtime.h>

#define TT 64
#define DIM 13
#define NSEQ 128
#define NPAIRS 8128          // 128*127/2 upper-triangle pairs (soft-DTW is symmetric)
#define INFV 1e10f
#define C_EXP 14.4269504088896f     // log2(e)/gamma ; R kept in scaled domain S = R*C_EXP
#define C_INV 0.06931471805599453f  // gamma*ln2 = 1/C_EXP

typedef _Float16 h2 __attribute__((ext_vector_type(2)));

__device__ __forceinline__ float fdot2(h2 a, h2 b, float c) {
#if __has_builtin(__builtin_amdgcn_fdot2)
    return __builtin_amdgcn_fdot2(a, b, c, false);
#else
    return c + (float)a.x * (float)b.x + (float)a.y * (float)b.y;
#endif
}

__global__ __launch_bounds__(256) void sdtw_pairs(const float* __restrict__ xxx,
                                                  const float* __restrict__ yyy,
                                                  float* __restrict__ simR) {
    __shared__ unsigned y2[4][7 * TT];   // component-major half2 y-data, conflict-free reads
    const int wave = threadIdx.x >> 6;
    const int lane = threadIdx.x & 63;
    const int t = blockIdx.x * 4 + wave;         // 0..8127

    // decode t -> (a,b) with a<b ; count(a) = a*(255-a)/2 pairs precede row a
    int a = (int)((255.0f - sqrtf(65025.0f - 8.0f * (float)t)) * 0.5f);
    if (a < 0) a = 0;
    if (a > 126) a = 126;
    while (a * (255 - a) / 2 > t) a--;
    while ((a + 1) * (254 - a) / 2 <= t) a++;
    const int b = a + 1 + (t - a * (255 - a) / 2);

    const float* fa = (a < 64) ? xxx + (size_t)a * TT * DIM : yyy + (size_t)(a - 64) * TT * DIM;
    const float* fb = (b < 64) ? xxx + (size_t)b * TT * DIM : yyy + (size_t)(b - 64) * TT * DIM;

    float xv[DIM], yv[DIM];
    float sqx = 0.f, sqy = 0.f;
#pragma unroll
    for (int c = 0; c < DIM; c++) {
        xv[c] = fa[lane * DIM + c];
        yv[c] = fb[lane * DIM + c];
        sqx += xv[c] * xv[c];
        sqy += yv[c] * yv[c];
    }
    // x side: pairs of (-2x) ; last pair (-2x12, 1.0) so dot picks up sqy from y side
    h2 xh[7];
#pragma unroll
    for (int c = 0; c < 6; c++) {
        h2 p; p.x = (_Float16)(-2.f * xv[2 * c]); p.y = (_Float16)(-2.f * xv[2 * c + 1]);
        xh[c] = p;
    }
    { h2 p; p.x = (_Float16)(-2.f * xv[12]); p.y = (_Float16)1.0f; xh[6] = p; }

    unsigned* yw = &y2[wave][0];
#pragma unroll
    for (int c = 0; c < 6; c++) {
        h2 p; p.x = (_Float16)yv[2 * c]; p.y = (_Float16)yv[2 * c + 1];
        yw[c * TT + lane] = __builtin_bit_cast(unsigned, p);
    }
    { h2 p; p.x = (_Float16)yv[12]; p.y = (_Float16)sqy; yw[6 * TT + lane] = __builtin_bit_cast(unsigned, p); }
    __syncthreads();

    // DP in scaled domain: S = R * C_EXP.  dg_{k+1} == up_k (diag pred = prev shfl).
    float S = INFV;
    float dg = (lane == 0) ? 0.f : INFV;   // corner injected at k=0, lane0
    const bool lane0 = (lane == 0);
    int j = -lane;
#pragma unroll 4
    for (int k = 0; k < 2 * TT - 1; k++, j++) {
        const bool valid = ((unsigned)j < (unsigned)TT);
        const int jc = j & (TT - 1);
        float acc = sqx;   // + sqy + -2*dot, via 7 packed fp16 dot2s
#pragma unroll
        for (int c = 0; c < 7; c++) {
            h2 yp = __builtin_bit_cast(h2, yw[c * TT + jc]);
            acc = fdot2(xh[c], yp, acc);
        }
        float up = __shfl_up(S, 1);
        up = lane0 ? INFV : up;
        float left = S;
        float m = fminf(fminf(up, left), dg);
        float sum = __builtin_amdgcn_exp2f(m - up)
                  + __builtin_amdgcn_exp2f(m - left)
                  + __builtin_amdgcn_exp2f(m - dg);
        float sm = m - __builtin_amdgcn_logf(sum);     // log2; gamma*ln2*C_EXP == 1
        float Sn = valid ? fmaf(acc, C_EXP, sm) : INFV;
        dg = up;
        S = Sn;
    }
    if (lane == 63) {
        float r = S * C_INV;
        simR[a * NSEQ + b] = r;
        simR[b * NSEQ + a] = r;     // symmetry
    }
}

// one wave per row: lse(row) - positive ; result parked in the (unused) diagonal
__global__ void row_lse(float* __restrict__ simR) {
    const int r = blockIdx.x;
    const int lane = threadIdx.x;
    const float* rowp = simR + r * NSEQ;
    float v0 = (lane == r) ? 0.f : 2.f * rowp[lane];
    const int c1 = lane + 64;
    float v1 = (c1 == r) ? 0.f : 2.f * rowp[c1];
    float mx = fmaxf(v0, v1);
#pragma unroll
    for (int o = 32; o; o >>= 1) mx = fmaxf(mx, __shfl_xor(mx, o));
    float s = __builtin_amdgcn_exp2f((v0 - mx) * 1.4426950408889634f)
            + __builtin_amdgcn_exp2f((v1 - mx) * 1.4426950408889634f);
#pragma unroll
    for (int o = 32; o; o >>= 1) s += __shfl_xor(s, o);
    if (lane == 0) {
        const int i = r & 63;
        float pos = 2.f * simR[i * NSEQ + i + 64];
        simR[r * NSEQ + r] = mx + 0.6931471805599453f * __builtin_amdgcn_logf(s) - pos;
    }
}

__global__ void final_loss(const float* __restrict__ simR, float* __restrict__ out) {
    __shared__ float red[NSEQ];
    const int tid = threadIdx.x;
    red[tid] = simR[tid * NSEQ + tid];
    __syncthreads();
    if (tid == 0) {
        float tsum = 0.f;
        for (int c = 0; c < NSEQ; c++) tsum += red[c];
        out[0] = tsum * (1.0f / NSEQ);
    }
}

extern "C" void kernel_launch(void* const* d_in, const int* in_sizes, int n_in,
                              void* d_out, int out_size, void* d_ws, size_t ws_size,
                              hipStream_t stream) {
    const float* xxx = (const float*)d_in[0];
    const float* yyy = (const float*)d_in[1];
    float* out = (float*)d_out;
    float* simR = (float*)d_ws;   // 16384 floats = 64 KB

    sdtw_pairs<<<NPAIRS / 4, 256, 0, stream>>>(xxx, yyy, simR);
    row_lse<<<NSEQ, 64, 0, stream>>>(simR);
    final_loss<<<1, NSEQ, 0, stream>>>(simR, out);
}

// Round 3
// 58.229 us; speedup vs baseline: 2.5760x; 1.0879x over previous
//
#include <hip/hip_runtime.h>

#define TT 64
#define DIM 13
#define NSEQ 128
#define NCHAIN 4096          // sum over b of ceil(b/2), b=1..127  (a<b pairs, chained in 2s)
#define INFV 1e10f
#define C_EXP 14.4269504088896f     // log2(e)/gamma ; S = R*C_EXP (scaled log domain)
#define C_INV 0.06931471805599453f  // gamma*ln2
#define XSTR 10   // dwords per LDS x-row (40B): gcd(10,32)=2 -> 4 lanes/bank-pair on b64 reads = free

typedef _Float16 h2 __attribute__((ext_vector_type(2)));

__device__ __forceinline__ float fdot2(h2 a, h2 b, float c) {
#if __has_builtin(__builtin_amdgcn_fdot2)
    return __builtin_amdgcn_fdot2(a, b, c, false);
#else
    return c + (float)a.x * (float)b.x + (float)a.y * (float)b.y;
#endif
}

__device__ __forceinline__ h2 mkh2(float a, float b) {
    h2 p; p.x = (_Float16)a; p.y = (_Float16)b; return p;
}

__global__ __launch_bounds__(256) void sdtw_pairs(const float* __restrict__ xxx,
                                                  const float* __restrict__ yyy,
                                                  float* __restrict__ simR) {
    __shared__ __align__(16) unsigned xl[4][128 * XSTR];
    const int wave = threadIdx.x >> 6;
    const int lane = threadIdx.x & 63;
    const int t = blockIdx.x * 4 + wave;          // chain id 0..4095

    // chain -> (b, a0): chains before column b: F(b-1) = floor(b^2/4)
    int b = (int)(2.0f * sqrtf((float)t + 1.0f));
    if (b < 1) b = 1;
    if (b > 127) b = 127;
    while (((b * b) >> 2) > t) b--;
    while ((((b + 1) * (b + 1)) >> 2) <= t) b++;
    const int a0 = 2 * (t - ((b * b) >> 2));
    const bool hasB = (a0 + 1 < b);

    const float* fb = ((b < 64) ? xxx + (size_t)b * TT * DIM
                                : yyy + (size_t)(b - 64) * TT * DIM) + lane * DIM;
    // y (column side) resident in registers: pairs (y0,y1)..(y10,y11),(y12,1)
    float sqy = 0.f, yv[DIM];
#pragma unroll
    for (int c = 0; c < DIM; c++) { yv[c] = fb[c]; sqy += yv[c] * yv[c]; }
    h2 yh[7];
#pragma unroll
    for (int c = 0; c < 6; c++) yh[c] = mkh2(yv[2 * c], yv[2 * c + 1]);
    yh[6] = mkh2(yv[12], 1.0f);

    // x rows (streamed side): rows 0..63 = seq a0, rows 64..127 = seq a0+1 (may be ==b; discarded)
    unsigned* xw = &xl[wave][0];
#pragma unroll
    for (int rr = 0; rr < 2; rr++) {
        const int r = lane + 64 * rr;
        const int s = rr ? (a0 + 1) : a0;
        const float* fx = ((s < 64) ? xxx + (size_t)s * TT * DIM
                                    : yyy + (size_t)(s - 64) * TT * DIM) + (r & 63) * DIM;
        float xv[DIM], sqx = 0.f;
#pragma unroll
        for (int c = 0; c < DIM; c++) { xv[c] = fx[c]; sqx += xv[c] * xv[c]; }
        unsigned* row = xw + r * XSTR;
#pragma unroll
        for (int c = 0; c < 6; c++)
            row[c] = __builtin_bit_cast(unsigned, mkh2(-2.f * xv[2 * c], -2.f * xv[2 * c + 1]));
        row[6] = __builtin_bit_cast(unsigned, mkh2(-2.f * xv[12], sqx));
    }
    __syncthreads();

    // DP: lane = column j; i' = global row index over the chain (64 rows per pair)
    float S = INFV, dgc = INFV;
    const float dgp = (lane == 0) ? 0.f : INFV;   // dg at a pair's row 0
    const bool lane0 = (lane == 0);
    int ip = -lane;

#pragma unroll 2
    for (int k = 0; k < 2 * 64 + 63; k++, ip++) {
        int ic = ip < 0 ? 0 : (ip > 127 ? 127 : ip);
        const unsigned* rp = xw + ic * XSTR;
        uint2 w0 = *(const uint2*)(rp);
        uint2 w1 = *(const uint2*)(rp + 2);
        uint2 w2 = *(const uint2*)(rp + 4);
        unsigned w3 = rp[6];

        float acc = sqy;
        acc = fdot2(yh[0], __builtin_bit_cast(h2, w0.x), acc);
        acc = fdot2(yh[1], __builtin_bit_cast(h2, w0.y), acc);
        acc = fdot2(yh[2], __builtin_bit_cast(h2, w1.x), acc);
        acc = fdot2(yh[3], __builtin_bit_cast(h2, w1.y), acc);
        acc = fdot2(yh[4], __builtin_bit_cast(h2, w2.x), acc);
        acc = fdot2(yh[5], __builtin_bit_cast(h2, w2.y), acc);
        acc = fdot2(yh[6], __builtin_bit_cast(h2, w3), acc);

        const bool p = ((ip & 63) == 0);          // first row of a pair
        float upv = p ? INFV : S;                 // up = own previous S
        float lf = __shfl_up(S, 1);
        lf = lane0 ? INFV : lf;
        float dgv = p ? dgp : dgc;

        float m   = fminf(fminf(upv, lf), dgv);
        float med = __builtin_amdgcn_fmed3f(upv, lf, dgv);
        float M   = fmaxf(fmaxf(upv, lf), dgv);
        float sum = 1.0f + __builtin_amdgcn_exp2f(m - med) + __builtin_amdgcn_exp2f(m - M);
        float sm  = m - __builtin_amdgcn_logf(sum);     // v_log_f32 = log2

        float Sn = fmaf(acc, C_EXP, sm);
        S = ((unsigned)ip < 128u) ? Sn : INFV;
        dgc = lf;

        if (lane == 63 && (ip == 63 || (ip == 127 && hasB))) {
            const int aa = a0 + (ip >> 6);
            const float r = S * C_INV;
            simR[aa * NSEQ + b] = r;
            simR[b * NSEQ + aa] = r;
        }
    }
}

// one wave per row: lse(row) - positive ; result parked in the (unused) diagonal
__global__ void row_lse(float* __restrict__ simR) {
    const int r = blockIdx.x;
    const int lane = threadIdx.x;
    const float* rowp = simR + r * NSEQ;
    float v0 = (lane == r) ? 0.f : 2.f * rowp[lane];
    const int c1 = lane + 64;
    float v1 = (c1 == r) ? 0.f : 2.f * rowp[c1];
    float mx = fmaxf(v0, v1);
#pragma unroll
    for (int o = 32; o; o >>= 1) mx = fmaxf(mx, __shfl_xor(mx, o));
    float s = __builtin_amdgcn_exp2f((v0 - mx) * 1.4426950408889634f)
            + __builtin_amdgcn_exp2f((v1 - mx) * 1.4426950408889634f);
#pragma unroll
    for (int o = 32; o; o >>= 1) s += __shfl_xor(s, o);
    if (lane == 0) {
        const int i = r & 63;
        float pos = 2.f * simR[i * NSEQ + i + 64];
        simR[r * NSEQ + r] = mx + 0.6931471805599453f * __builtin_amdgcn_logf(s) - pos;
    }
}

__global__ void final_loss(const float* __restrict__ simR, float* __restrict__ out) {
    __shared__ float red[NSEQ];
    const int tid = threadIdx.x;
    red[tid] = simR[tid * NSEQ + tid];
    __syncthreads();
    if (tid == 0) {
        float tsum = 0.f;
        for (int c = 0; c < NSEQ; c++) tsum += red[c];
        out[0] = tsum * (1.0f / NSEQ);
    }
}

extern "C" void kernel_launch(void* const* d_in, const int* in_sizes, int n_in,
                              void* d_out, int out_size, void* d_ws, size_t ws_size,
                              hipStream_t stream) {
    const float* xxx = (const float*)d_in[0];
    const float* yyy = (const float*)d_in[1];
    float* out = (float*)d_out;
    float* simR = (float*)d_ws;   // 16384 floats = 64 KB

    sdtw_pairs<<<NCHAIN / 4, 256, 0, stream>>>(xxx, yyy, simR);
    row_lse<<<NSEQ, 64, 0, stream>>>(simR);
    final_loss<<<1, NSEQ, 0, stream>>>(simR, out);
}

// Round 4
// 51.977 us; speedup vs baseline: 2.8859x; 1.1203x over previous
//
#include <hip/hip_runtime.h>

#define TT 64
#define DIM 13
#define NSEQ 128
#define NPAIRS 8128          // 128*127/2 upper-triangle pairs (soft-DTW is symmetric)
#define INFV 1e10f
#define C_EXP 14.4269504088896f     // log2(e)/gamma ; S = R*C_EXP (scaled log2 domain)
#define C_INV 0.06931471805599453f  // gamma*ln2

typedef _Float16 h2 __attribute__((ext_vector_type(2)));

__device__ __forceinline__ float fdot2(h2 a, h2 b, float c) {
#if __has_builtin(__builtin_amdgcn_fdot2)
    return __builtin_amdgcn_fdot2(a, b, c, false);
#else
    return c + (float)a.x * (float)b.x + (float)a.y * (float)b.y;
#endif
}
__device__ __forceinline__ h2 mkh2(float a, float b) {
    h2 p; p.x = (_Float16)a; p.y = (_Float16)b; return p;
}

__global__ __launch_bounds__(256) void sdtw_pairs(const float* __restrict__ xxx,
                                                  const float* __restrict__ yyy,
                                                  float* __restrict__ simR) {
    // component-major x-tile: [7 comps][4 waves][64 rows] dwords -> 7 ds_read_b32
    // per step off one shared vaddr (+1024B imm per comp); 2-way bank alias = free.
    __shared__ unsigned xl[7 * 4 * TT];
    const int wave = threadIdx.x >> 6;
    const int lane = threadIdx.x & 63;
    const int t = blockIdx.x * 4 + wave;          // pair id 0..8127

    // decode t -> (a,b), a<b ; pairs before row a: a*(255-a)/2
    int a = (int)((255.0f - sqrtf(65025.0f - 8.0f * (float)t)) * 0.5f);
    if (a < 0) a = 0;
    if (a > 126) a = 126;
    while (a * (255 - a) / 2 > t) a--;
    while ((a + 1) * (254 - a) / 2 <= t) a++;
    const int b = a + 1 + (t - a * (255 - a) / 2);

    // lane = column j, holds y_j (seq b frame j) in registers
    const float* fb = ((b < 64) ? xxx + (size_t)b * TT * DIM
                                : yyy + (size_t)(b - 64) * TT * DIM) + lane * DIM;
    float sqy = 0.f, yv[DIM];
#pragma unroll
    for (int c = 0; c < DIM; c++) { yv[c] = fb[c]; sqy += yv[c] * yv[c]; }
    h2 yh[7];
#pragma unroll
    for (int c = 0; c < 6; c++) yh[c] = mkh2(yv[2 * c], yv[2 * c + 1]);
    yh[6] = mkh2(yv[12], 1.0f);

    // x side (seq a) staged to LDS: pairs of (-2x), last pair (-2x12, sqx)
    {
        const float* fx = ((a < 64) ? xxx + (size_t)a * TT * DIM
                                    : yyy + (size_t)(a - 64) * TT * DIM) + lane * DIM;
        float xv[DIM], sqx = 0.f;
#pragma unroll
        for (int c = 0; c < DIM; c++) { xv[c] = fx[c]; sqx += xv[c] * xv[c]; }
        unsigned* row = xl + wave * TT + lane;
#pragma unroll
        for (int c = 0; c < 6; c++)
            row[c * 256] = __builtin_bit_cast(unsigned, mkh2(-2.f * xv[2 * c], -2.f * xv[2 * c + 1]));
        row[6 * 256] = __builtin_bit_cast(unsigned, mkh2(-2.f * xv[12], sqx));
    }
    __syncthreads();

    // DP over anti-diagonals. Lane j at step k handles cell (i=k-j, j).
    //   up  = R(i-1,j)   = own S (previous step)
    //   left= R(i,j-1)   = shfl_up(S,1)        (INF at lane 0)
    //   diag= R(i-1,j-1) = previous step's left
    // No validity predicates: inactive lanes' S stays ~INFV (1e10) and its
    // exp2 terms underflow to 0; drift over the ramp is O(100) on 1e10.
    const unsigned* xw = xl + wave * TT;
    float S = INFV;
    float dgc = (lane == 0) ? 0.f : INFV;     // corner injected at (0,0)
    const bool lane0 = (lane == 0);
    int jc = (-lane) & (TT - 1);              // streamed row index (mod 64)

#pragma unroll 4
    for (int k = 0; k < 2 * TT - 1; k++) {
        float acc = sqy;
        acc = fdot2(yh[0], __builtin_bit_cast(h2, xw[jc]),            acc);
        acc = fdot2(yh[1], __builtin_bit_cast(h2, xw[jc + 1 * 256]),  acc);
        acc = fdot2(yh[2], __builtin_bit_cast(h2, xw[jc + 2 * 256]),  acc);
        acc = fdot2(yh[3], __builtin_bit_cast(h2, xw[jc + 3 * 256]),  acc);
        acc = fdot2(yh[4], __builtin_bit_cast(h2, xw[jc + 4 * 256]),  acc);
        acc = fdot2(yh[5], __builtin_bit_cast(h2, xw[jc + 5 * 256]),  acc);
        acc = fdot2(yh[6], __builtin_bit_cast(h2, xw[jc + 6 * 256]),  acc);
        jc = (jc + 1) & (TT - 1);

        float lf = __shfl_up(S, 1);
        lf = lane0 ? INFV : lf;
        float up = S;

        float m   = fminf(fminf(up, lf), dgc);
        float med = __builtin_amdgcn_fmed3f(up, lf, dgc);
        float M   = fmaxf(fmaxf(up, lf), dgc);
        float sum = 1.0f + __builtin_amdgcn_exp2f(m - med)
                         + __builtin_amdgcn_exp2f(m - M);
        S = fmaf(acc, C_EXP, m - __builtin_amdgcn_logf(sum));   // v_log_f32 = log2
        dgc = lf;
    }

    if (lane == 63) {
        const float r = S * C_INV;            // lane 63 at k=126 holds R(63,63)
        simR[a * NSEQ + b] = r;
        simR[b * NSEQ + a] = r;
    }
}

// one wave per row: lse(row) - positive ; result parked in the (unused) diagonal
__global__ void row_lse(float* __restrict__ simR) {
    const int r = blockIdx.x;
    const int lane = threadIdx.x;
    const float* rowp = simR + r * NSEQ;
    float v0 = (lane == r) ? 0.f : 2.f * rowp[lane];
    const int c1 = lane + 64;
    float v1 = (c1 == r) ? 0.f : 2.f * rowp[c1];
    float mx = fmaxf(v0, v1);
#pragma unroll
    for (int o = 32; o; o >>= 1) mx = fmaxf(mx, __shfl_xor(mx, o));
    float s = __builtin_amdgcn_exp2f((v0 - mx) * 1.4426950408889634f)
            + __builtin_amdgcn_exp2f((v1 - mx) * 1.4426950408889634f);
#pragma unroll
    for (int o = 32; o; o >>= 1) s += __shfl_xor(s, o);
    if (lane == 0) {
        const int i = r & 63;
        float pos = 2.f * simR[i * NSEQ + i + 64];
        simR[r * NSEQ + r] = mx + 0.6931471805599453f * __builtin_amdgcn_logf(s) - pos;
    }
}

__global__ void final_loss(const float* __restrict__ simR, float* __restrict__ out) {
    __shared__ float red[NSEQ];
    const int tid = threadIdx.x;
    red[tid] = simR[tid * NSEQ + tid];
    __syncthreads();
    if (tid == 0) {
        float tsum = 0.f;
        for (int c = 0; c < NSEQ; c++) tsum += red[c];
        out[0] = tsum * (1.0f / NSEQ);
    }
}

extern "C" void kernel_launch(void* const* d_in, const int* in_sizes, int n_in,
                              void* d_out, int out_size, void* d_ws, size_t ws_size,
                              hipStream_t stream) {
    const float* xxx = (const float*)d_in[0];
    const float* yyy = (const float*)d_in[1];
    float* out = (float*)d_out;
    float* simR = (float*)d_ws;   // 16384 floats = 64 KB

    sdtw_pairs<<<NPAIRS / 4, 256, 0, stream>>>(xxx, yyy, simR);
    row_lse<<<NSEQ, 64, 0, stream>>>(simR);
    final_loss<<<1, NSEQ, 0, stream>>>(simR, out);
}

// Round 5
// 50.272 us; speedup vs baseline: 2.9837x; 1.0339x over previous
//
#include <hip/hip_runtime.h>

#define TT 64
#define DIM 13
#define NSEQ 128
#define NWAVE 4096           // sum over a of ceil((127-a)/2): 2 pairs per wave, shared a
#define INFV 1e10f
#define C_EXP 14.4269504088896f     // log2(e)/gamma ; S = R*C_EXP (scaled log2 domain)
#define C_INV 0.06931471805599453f  // gamma*ln2

typedef _Float16 h2 __attribute__((ext_vector_type(2)));

__device__ __forceinline__ float fdot2(h2 a, h2 b, float c) {
#if __has_builtin(__builtin_amdgcn_fdot2)
    return __builtin_amdgcn_fdot2(a, b, c, false);
#else
    return c + (float)a.x * (float)b.x + (float)a.y * (float)b.y;
#endif
}
__device__ __forceinline__ h2 mkh2(float a, float b) {
    h2 p; p.x = (_Float16)a; p.y = (_Float16)b; return p;
}
// lane i <- lane i-1, lane 0 <- INFV. v_mov_b32 dpp wave_shr:1 (full-rate VALU, no DS op)
__device__ __forceinline__ float shr1_inf(float x) {
    int r = __builtin_amdgcn_update_dpp(__builtin_bit_cast(int, INFV),
                                        __builtin_bit_cast(int, x),
                                        0x138, 0xf, 0xf, false);
    return __builtin_bit_cast(float, r);
}

__global__ __launch_bounds__(256) void sdtw_pairs(const float* __restrict__ xxx,
                                                  const float* __restrict__ yyy,
                                                  float* __restrict__ simR) {
    // component-major x-tile: [7 comps][4 waves][64 rows] dwords; anti-diagonal
    // b32 reads are 2-way bank-aliased = free.
    __shared__ unsigned xl[7 * 4 * TT];
    const int wave = threadIdx.x >> 6;
    const int lane = threadIdx.x & 63;
    const int t = blockIdx.x * 4 + wave;          // wave id 0..4095

    // decode t -> (a, q): C(a) = 64a - floor(a^2/4) waves precede row a
    int a = 128 - (int)sqrtf(16384.0f - 4.0f * (float)t);
    if (a < 0) a = 0;
    if (a > 126) a = 126;
    while (64 * a - ((a * a) >> 2) > t) a--;
    while (64 * (a + 1) - (((a + 1) * (a + 1)) >> 2) <= t) a++;
    const int q = t - (64 * a - ((a * a) >> 2));
    const int b1 = a + 1 + 2 * q;
    const int b2 = (b1 < 127) ? b1 + 1 : b1;      // dup when row has odd partner count

    // lane = column j: y_j of both partner sequences in registers
    h2 yh1[7], yh2[7];
    float sqy1 = 0.f, sqy2 = 0.f;
    {
        const float* f1 = ((b1 < 64) ? xxx + (size_t)b1 * TT * DIM
                                     : yyy + (size_t)(b1 - 64) * TT * DIM) + lane * DIM;
        const float* f2 = ((b2 < 64) ? xxx + (size_t)b2 * TT * DIM
                                     : yyy + (size_t)(b2 - 64) * TT * DIM) + lane * DIM;
        float v1[DIM], v2[DIM];
#pragma unroll
        for (int c = 0; c < DIM; c++) {
            v1[c] = f1[c]; sqy1 += v1[c] * v1[c];
            v2[c] = f2[c]; sqy2 += v2[c] * v2[c];
        }
#pragma unroll
        for (int c = 0; c < 6; c++) {
            yh1[c] = mkh2(v1[2 * c], v1[2 * c + 1]);
            yh2[c] = mkh2(v2[2 * c], v2[2 * c + 1]);
        }
        yh1[6] = mkh2(v1[12], 1.0f);
        yh2[6] = mkh2(v2[12], 1.0f);
    }

    // x side (seq a, shared by both pairs) staged to LDS: (-2x) pairs, last (-2x12, sqx)
    {
        const float* fx = ((a < 64) ? xxx + (size_t)a * TT * DIM
                                    : yyy + (size_t)(a - 64) * TT * DIM) + lane * DIM;
        float xv[DIM], sqx = 0.f;
#pragma unroll
        for (int c = 0; c < DIM; c++) { xv[c] = fx[c]; sqx += xv[c] * xv[c]; }
        unsigned* row = xl + wave * TT + lane;
#pragma unroll
        for (int c = 0; c < 6; c++)
            row[c * 256] = __builtin_bit_cast(unsigned, mkh2(-2.f * xv[2 * c], -2.f * xv[2 * c + 1]));
        row[6 * 256] = __builtin_bit_cast(unsigned, mkh2(-2.f * xv[12], sqx));
    }
    __syncthreads();

    // Two interleaved DPs (shared x-stream). Lane j at step k handles cell (k-j, j).
    // up = own previous S; left = wave_shr:1 of S (INFV at lane 0); diag = prev left.
    // No validity predicates: inactive lanes ride at ~INFV, their exp2 terms underflow.
    const unsigned* xw = xl + wave * TT;
    float S1 = INFV, S2 = INFV;
    float dg1 = (lane == 0) ? 0.f : INFV;
    float dg2 = dg1;
    int jc = (-lane) & (TT - 1);

#pragma unroll 2
    for (int k = 0; k < 2 * TT - 1; k++) {
        unsigned w0 = xw[jc];
        unsigned w1 = xw[jc + 1 * 256];
        unsigned w2 = xw[jc + 2 * 256];
        unsigned w3 = xw[jc + 3 * 256];
        unsigned w4 = xw[jc + 4 * 256];
        unsigned w5 = xw[jc + 5 * 256];
        unsigned w6 = xw[jc + 6 * 256];
        jc = (jc + 1) & (TT - 1);

        float acc1 = sqy1, acc2 = sqy2;
        acc1 = fdot2(yh1[0], __builtin_bit_cast(h2, w0), acc1);
        acc2 = fdot2(yh2[0], __builtin_bit_cast(h2, w0), acc2);
        acc1 = fdot2(yh1[1], __builtin_bit_cast(h2, w1), acc1);
        acc2 = fdot2(yh2[1], __builtin_bit_cast(h2, w1), acc2);
        acc1 = fdot2(yh1[2], __builtin_bit_cast(h2, w2), acc1);
        acc2 = fdot2(yh2[2], __builtin_bit_cast(h2, w2), acc2);
        acc1 = fdot2(yh1[3], __builtin_bit_cast(h2, w3), acc1);
        acc2 = fdot2(yh2[3], __builtin_bit_cast(h2, w3), acc2);
        acc1 = fdot2(yh1[4], __builtin_bit_cast(h2, w4), acc1);
        acc2 = fdot2(yh2[4], __builtin_bit_cast(h2, w4), acc2);
        acc1 = fdot2(yh1[5], __builtin_bit_cast(h2, w5), acc1);
        acc2 = fdot2(yh2[5], __builtin_bit_cast(h2, w5), acc2);
        acc1 = fdot2(yh1[6], __builtin_bit_cast(h2, w6), acc1);
        acc2 = fdot2(yh2[6], __builtin_bit_cast(h2, w6), acc2);

        float lf1 = shr1_inf(S1);
        float lf2 = shr1_inf(S2);

        float m1   = fminf(fminf(S1, lf1), dg1);
        float m2   = fminf(fminf(S2, lf2), dg2);
        float md1  = __builtin_amdgcn_fmed3f(S1, lf1, dg1);
        float md2  = __builtin_amdgcn_fmed3f(S2, lf2, dg2);
        float M1   = fmaxf(fmaxf(S1, lf1), dg1);
        float M2   = fmaxf(fmaxf(S2, lf2), dg2);
        float sum1 = 1.0f + __builtin_amdgcn_exp2f(m1 - md1) + __builtin_amdgcn_exp2f(m1 - M1);
        float sum2 = 1.0f + __builtin_amdgcn_exp2f(m2 - md2) + __builtin_amdgcn_exp2f(m2 - M2);
        S1 = fmaf(acc1, C_EXP, m1 - __builtin_amdgcn_logf(sum1));   // v_log_f32 = log2
        S2 = fmaf(acc2, C_EXP, m2 - __builtin_amdgcn_logf(sum2));
        dg1 = lf1;
        dg2 = lf2;
    }

    if (lane == 63) {
        const float r1 = S1 * C_INV;
        const float r2 = S2 * C_INV;
        simR[a * NSEQ + b1] = r1;
        simR[b1 * NSEQ + a] = r1;
        simR[a * NSEQ + b2] = r2;
        simR[b2 * NSEQ + a] = r2;
    }
}

// one wave per row: lse(row) - positive ; result parked in the (unused) diagonal
__global__ void row_lse(float* __restrict__ simR) {
    const int r = blockIdx.x;
    const int lane = threadIdx.x;
    const float* rowp = simR + r * NSEQ;
    float v0 = (lane == r) ? 0.f : 2.f * rowp[lane];
    const int c1 = lane + 64;
    float v1 = (c1 == r) ? 0.f : 2.f * rowp[c1];
    float mx = fmaxf(v0, v1);
#pragma unroll
    for (int o = 32; o; o >>= 1) mx = fmaxf(mx, __shfl_xor(mx, o));
    float s = __builtin_amdgcn_exp2f((v0 - mx) * 1.4426950408889634f)
            + __builtin_amdgcn_exp2f((v1 - mx) * 1.4426950408889634f);
#pragma unroll
    for (int o = 32; o; o >>= 1) s += __shfl_xor(s, o);
    if (lane == 0) {
        const int i = r & 63;
        float pos = 2.f * simR[i * NSEQ + i + 64];
        simR[r * NSEQ + r] = mx + 0.6931471805599453f * __builtin_amdgcn_logf(s) - pos;
    }
}

__global__ void final_loss(const float* __restrict__ simR, float* __restrict__ out) {
    __shared__ float red[NSEQ];
    const int tid = threadIdx.x;
    red[tid] = simR[tid * NSEQ + tid];
    __syncthreads();
    if (tid == 0) {
        float tsum = 0.f;
        for (int c = 0; c < NSEQ; c++) tsum += red[c];
        out[0] = tsum * (1.0f / NSEQ);
    }
}

extern "C" void kernel_launch(void* const* d_in, const int* in_sizes, int n_in,
                              void* d_out, int out_size, void* d_ws, size_t ws_size,
                              hipStream_t stream) {
    const float* xxx = (const float*)d_in[0];
    const float* yyy = (const float*)d_in[1];
    float* out = (float*)d_out;
    float* simR = (float*)d_ws;   // 16384 floats = 64 KB

    sdtw_pairs<<<NWAVE / 4, 256, 0, stream>>>(xxx, yyy, simR);
    row_lse<<<NSEQ, 64, 0, stream>>>(simR);
    final_loss<<<1, NSEQ, 0, stream>>>(simR, out);
}